// Round 3
// baseline (360.706 us; speedup 1.0000x reference)
//
#include <hip/hip_runtime.h>

// VectorQuantizer on MI355X (gfx950), v4 (= v3 with phase-2 staging fix +
// 64KB LDS layout).
// 256-thr blocks, 4 waves, 64 rows (= one (b,h) line) per wave -> 4 MFMA per
// LDS B-read. Prologue loads A-fragments directly global->reg. Codebook
// staged in 32-code dbuf tiles via global_load_lds from pre-swizzled copy,
// counted vmcnt(4). Phase 2 fuses the block's 4 lines: per d one contiguous
// 1024B span store through a linear conflict-free LDS transpose buffer.

#define DIN 256

typedef __attribute__((ext_vector_type(8))) short short8;
typedef __attribute__((ext_vector_type(4))) float float4v;
typedef __attribute__((ext_vector_type(4))) unsigned short ushort4v;

static __device__ __forceinline__ unsigned short f2bf(float f) {
  unsigned int u = __float_as_uint(f);
  unsigned int r = (u + 0x7fffu + ((u >> 16) & 1u)) >> 16;  // RNE
  return (unsigned short)r;
}

// codebook fp32 -> bf16 PRE-SWIZZLED 32-code tiles (linear DMA lands in the
// XOR-swizzled layout the B ds_read_b128s expect) + per-code ||e||^2.
__global__ void vq_prep(const float* __restrict__ e,
                        unsigned short* __restrict__ e_pre,
                        float* __restrict__ norms) {
  int wave = threadIdx.x >> 6, lane = threadIdx.x & 63;
  int k = blockIdx.x * 4 + wave;
  const float4v* src = (const float4v*)(e + k * DIN);
  float4v v = src[lane];
  float ss = v[0]*v[0] + v[1]*v[1] + v[2]*v[2] + v[3]*v[3];
  ushort4v pk;
  pk[0] = f2bf(v[0]); pk[1] = f2bf(v[1]); pk[2] = f2bf(v[2]); pk[3] = f2bf(v[3]);
  int t = k >> 5, kL = k & 31;
  int cc = lane >> 1, half = lane & 1;       // 16B chunk, 8B half
  int s = cc ^ (kL & 7);
  *(ushort4v*)(e_pre + t * 8192 + kL * 256 + s * 8 + half * 4) = pk;
  #pragma unroll
  for (int m = 1; m < 64; m <<= 1) ss += __shfl_xor(ss, m, 64);
  if (lane == 0) norms[k] = ss;
}

#define BARRIER_RAW() do { asm volatile("" ::: "memory"); \
  __builtin_amdgcn_s_barrier(); asm volatile("" ::: "memory"); } while (0)

__global__ void __launch_bounds__(256, 2)
vq_main(const float* __restrict__ xin, const float* __restrict__ e_fp,
        const unsigned short* __restrict__ e_pre,
        const float* __restrict__ norms,
        float* __restrict__ out, float* __restrict__ loss_acc) {
  // GEMM phase: [0,32768) es dbuf (2x16KB) | [32768,36864) nrm[1024]
  //             [36864,37888) xna[256] | [37888,38912) fi[256] | [38912,+) prt[4]
  // Phase 2:    [0,65536) qs [64][256] f32 (everything above is dead by then)
  __shared__ char smem[65536];
  float* qs  = (float*)smem;
  float* nrm = (float*)(smem + 32768);
  float* xna = (float*)(smem + 36864);
  int*   fi  = (int*)(smem + 37888);
  float* prt = (float*)(smem + 38912);

  const int tid  = threadIdx.x;
  const int wave = tid >> 6, lane = tid & 63;
  const int m16  = lane & 15, quad = lane >> 4;
  const int line0 = blockIdx.x * 4;          // 4 (b,h) lines per block
  const int line  = line0 + wave;            // this wave's line
  const float* xl = xin + (line >> 6) * 1048576 + (line & 63) * 64;

  // stage tile t (16 KB) into buffer buf: 4 DMA issues/thread, linear dest
  auto stage = [&](int t, int buf) {
    const char* src = (const char*)e_pre + t * 16384;
    char* dst = smem + buf * 16384;
    #pragma unroll
    for (int j = 0; j < 4; ++j) {
      int off = j * 4096 + tid * 16;
      __builtin_amdgcn_global_load_lds(
          (const __attribute__((address_space(1))) unsigned int*)(src + off),
          (__attribute__((address_space(3))) unsigned int*)(dst + off),
          16, 0, 0);
    }
  };
  stage(0, 0);                               // overlap DMA with prologue

  nrm[tid]       = norms[tid];
  nrm[tid + 256] = norms[tid + 256];
  nrm[tid + 512] = norms[tid + 512];
  nrm[tid + 768] = norms[tid + 768];

  // ---- prologue: A-fragments direct global->reg + fp32 row norms ----
  short8 areg[32];                           // 4 rowfrags x 8 ksteps = 128 VGPR
  {
    float ssq[4] = {0.0f, 0.0f, 0.0f, 0.0f};
    #pragma unroll
    for (int i = 0; i < 4; ++i) {
      const float* p = xl + i * 16 + m16;    // row = i*16+m16 (w coordinate)
      #pragma unroll
      for (int kk = 0; kk < 8; ++kk) {
        int dbase = kk * 32 + quad * 8;
        short8 pk;
        #pragma unroll
        for (int ii = 0; ii < 8; ++ii) {
          float xv = p[(dbase + ii) * 4096];
          ssq[i] += xv * xv;
          pk[ii] = (short)f2bf(xv);
        }
        areg[i * 8 + kk] = pk;
      }
    }
    #pragma unroll
    for (int i = 0; i < 4; ++i) {            // reduce over quad lanes
      float s = ssq[i];
      s += __shfl_xor(s, 16, 64);
      s += __shfl_xor(s, 32, 64);
      if (quad == 0) xna[wave * 64 + i * 16 + m16] = s;
    }
  }

  float bestv[4][4];
  int   besti[4][4];
  #pragma unroll
  for (int i = 0; i < 4; ++i)
    #pragma unroll
    for (int r = 0; r < 4; ++r) { bestv[i][r] = INFINITY; besti[i][r] = 0; }

  // ---- GEMM: 32 code tiles, double-buffered, counted vmcnt ----
  for (int t = 0; t < 32; ++t) {
    if (t < 31) {
      stage(t + 1, (t + 1) & 1);
      asm volatile("s_waitcnt vmcnt(4)" ::: "memory");   // tile t landed
    } else {
      asm volatile("s_waitcnt vmcnt(0)" ::: "memory");
    }
    BARRIER_RAW();
    const unsigned short* eb = (const unsigned short*)(smem + (t & 1) * 16384);
    #pragma unroll
    for (int j = 0; j < 2; ++j) {
      int cL = j * 16 + m16;
      float4v a0 = (float4v)(0.0f), a1 = (float4v)(0.0f);
      float4v a2 = (float4v)(0.0f), a3 = (float4v)(0.0f);
      #pragma unroll
      for (int kk = 0; kk < 8; ++kk) {
        short8 bfr = *(const short8*)(eb + cL * 256 + 8 * ((kk * 4 + quad) ^ (cL & 7)));
        a0 = __builtin_amdgcn_mfma_f32_16x16x32_bf16(areg[kk],      bfr, a0, 0, 0, 0);
        a1 = __builtin_amdgcn_mfma_f32_16x16x32_bf16(areg[8 + kk],  bfr, a1, 0, 0, 0);
        a2 = __builtin_amdgcn_mfma_f32_16x16x32_bf16(areg[16 + kk], bfr, a2, 0, 0, 0);
        a3 = __builtin_amdgcn_mfma_f32_16x16x32_bf16(areg[24 + kk], bfr, a3, 0, 0, 0);
      }
      int col = t * 32 + cL;
      float nj = nrm[col];
      #pragma unroll
      for (int r = 0; r < 4; ++r) {
        float s0 = nj - 2.0f * a0[r];
        if (s0 < bestv[0][r]) { bestv[0][r] = s0; besti[0][r] = col; }
        float s1 = nj - 2.0f * a1[r];
        if (s1 < bestv[1][r]) { bestv[1][r] = s1; besti[1][r] = col; }
        float s2 = nj - 2.0f * a2[r];
        if (s2 < bestv[2][r]) { bestv[2][r] = s2; besti[2][r] = col; }
        float s3 = nj - 2.0f * a3[r];
        if (s3 < bestv[3][r]) { bestv[3][r] = s3; besti[3][r] = col; }
      }
    }
    BARRIER_RAW();
  }

  // ---- cross-lane argmin over the 16 col-lanes (tie -> smaller idx) ----
  #pragma unroll
  for (int msk = 1; msk <= 8; msk <<= 1) {
    #pragma unroll
    for (int i = 0; i < 4; ++i)
      #pragma unroll
      for (int r = 0; r < 4; ++r) {
        float ov = __shfl_xor(bestv[i][r], msk, 64);
        int   oi = __shfl_xor(besti[i][r], msk, 64);
        if (ov < bestv[i][r] || (ov == bestv[i][r] && oi < besti[i][r])) {
          bestv[i][r] = ov; besti[i][r] = oi;
        }
      }
  }

  // ---- indices + loss (loss = sum(||x||^2 + bestv), bestv = ||q||^2-2x.q) ----
  float lsum = 0.0f;
  if (m16 == 0) {
    #pragma unroll
    for (int i = 0; i < 4; ++i)
      #pragma unroll
      for (int r = 0; r < 4; ++r) {
        int row = wave * 64 + i * 16 + quad * 4 + r;
        fi[row] = besti[i][r];
        lsum += bestv[i][r] + xna[row];
      }
  }
  #pragma unroll
  for (int msk = 1; msk < 64; msk <<= 1) lsum += __shfl_xor(lsum, msk, 64);
  if (lane == 0) prt[wave] = lsum;
  __syncthreads();                           // fi/prt visible; GEMM LDS reads done
  if (tid == 0)
    atomicAdd(loss_acc, prt[0] + prt[1] + prt[2] + prt[3]);

  // ---- phase 2: gather fp32 e rows, 4 d-quarters through linear LDS
  //      transpose; per d one contiguous 1024B (4-line) span store ----
  const int b0 = line0 >> 6, h0 = line0 & 63;
  float* out1 = out + 1 + b0 * 1048576 + h0 * 64;
  const int myidx = fi[tid];                 // this thread owns row r = tid
  const float* er = e_fp + myidx * 256;
  __syncthreads();                           // fi/prt consumed; qs may overwrite
  for (int q = 0; q < 4; ++q) {
    if (q) __syncthreads();                  // prev quarter's reads done
    #pragma unroll
    for (int c = 0; c < 16; ++c) {           // stage 64 d-values of own row
      float4v qv = *(const float4v*)(er + q * 64 + c * 4);
      qs[(c * 4 + 0) * 256 + tid] = qv[0];
      qs[(c * 4 + 1) * 256 + tid] = qv[1];
      qs[(c * 4 + 2) * 256 + tid] = qv[2];
      qs[(c * 4 + 3) * 256 + tid] = qv[3];
    }
    __syncthreads();
    #pragma unroll
    for (int it = 0; it < 16; ++it) {
      int dl = it * 4 + wave;                // 0..63 within quarter
      float4v ov = *(const float4v*)(qs + dl * 256 + lane * 4);
      *(float4v*)(out1 + (q * 64 + dl) * 4096 + lane * 4) = ov;  // 1024B span
    }
  }
}

__global__ void vq_fin(const float* __restrict__ loss_acc,
                       const float* __restrict__ beta,
                       float* __restrict__ out) {
  out[0] = (1.0f + beta[0]) * loss_acc[0] / 33554432.0f;
}

extern "C" void kernel_launch(void* const* d_in, const int* in_sizes, int n_in,
                              void* d_out, int out_size, void* d_ws, size_t ws_size,
                              hipStream_t stream) {
  const float* xin  = (const float*)d_in[0];
  const float* emb  = (const float*)d_in[1];
  const float* beta = (const float*)d_in[2];
  float* out = (float*)d_out;
  float* loss_acc = (float*)d_ws;                                // 4 B
  float* norms = (float*)((char*)d_ws + 4096);                   // 4 KB
  unsigned short* e_pre = (unsigned short*)((char*)d_ws + 8192); // 512 KB

  hipMemsetAsync(d_ws, 0, 4, stream);
  vq_prep<<<256, 256, 0, stream>>>(emb, e_pre, norms);
  vq_main<<<512, 256, 0, stream>>>(xin, emb, e_pre, norms, out, loss_acc);
  vq_fin<<<1, 1, 0, stream>>>(loss_acc, beta, out);
}